// Round 1
// baseline (1458.843 us; speedup 1.0000x reference)
//
#include <hip/hip_runtime.h>
#include <math.h>

// Problem constants (fixed by the reference)
#define N_NODES 512
#define HDIM    1024
#define K1      4096          // B*H
#define EDGES   16384
#define NN      (N_NODES*N_NODES)   // 262144
#define NH      (N_NODES*HDIM)      // 524288
#define NP1     513
#define CHUNKS  128
#define CHUNK_LEN (NH/CHUNKS)       // 4096

typedef _Float16 f16;
typedef f16  f16x8 __attribute__((ext_vector_type(8)));
typedef float f32x4 __attribute__((ext_vector_type(4)));

// ---------------------------------------------------------------------------
// 1) A[i][j] = X[n][h] + img[b][h]  with the reshape mapping:
//    b = i>>7, n = (i&127)*4 + (j>>10), h = j&1023     (f16 output)
// ---------------------------------------------------------------------------
__global__ __launch_bounds__(256) void build_A(const float* __restrict__ X,
                                               const float* __restrict__ img,
                                               f16* __restrict__ A) {
    int idx = blockIdx.x * 256 + threadIdx.x;      // grid sized exactly 512*4096
    int i = idx >> 12, j = idx & 4095;
    int n = ((i & 127) << 2) + (j >> 10);
    int h = j & 1023;
    int b = i >> 7;
    A[idx] = (f16)(X[n * HDIM + h] + img[b * HDIM + h]);
}

// ---------------------------------------------------------------------------
// 2) Wt[n][k] = (f16) W[k][n]   (transpose+cast, LDS tiled, pad to kill
//    bank conflicts)
// ---------------------------------------------------------------------------
__global__ __launch_bounds__(256) void build_Wt(const float* __restrict__ W,
                                                f16* __restrict__ Wt) {
    __shared__ float tile[64][65];
    int k0 = blockIdx.x * 64, n0 = blockIdx.y * 64;
    int tx = threadIdx.x & 63, ty = threadIdx.x >> 6;
#pragma unroll
    for (int r = 0; r < 16; ++r) {
        int row = ty + (r << 2);
        tile[row][tx] = W[(size_t)(k0 + row) * HDIM + n0 + tx];
    }
    __syncthreads();
#pragma unroll
    for (int r = 0; r < 16; ++r) {
        int row = ty + (r << 2);
        Wt[(size_t)(n0 + row) * K1 + k0 + tx] = (f16)tile[tx][row];
    }
}

// ---------------------------------------------------------------------------
// 3) Generic f16 MFMA GEMM: C(MxN, f32) = A(MxK) @ Bt(NxK)^T
//    Wave tile 32x64 (2x4 frags of 16x16x32). Operands straight from L2.
//    Layouts (verified, guide §3): A-frag A[m=lane&15][k=(lane>>4)*8+j],
//    B-frag Bt[n=lane&15][k=(lane>>4)*8+j], C/D col=lane&15,row=(lane>>4)*4+r.
// ---------------------------------------------------------------------------
__global__ __launch_bounds__(256) void gemm_f16(const f16* __restrict__ A,
                                                const f16* __restrict__ Bt,
                                                float* __restrict__ C,
                                                int Ncols, int K,
                                                int lda, int ldb, int ldc) {
    int wid  = blockIdx.x * 4 + (threadIdx.x >> 6);
    int lane = threadIdx.x & 63;
    int wavesN = Ncols >> 6;
    int wm = wid / wavesN, wn = wid % wavesN;
    int lr = lane & 15, lq = lane >> 4;

    const f16* a0 = A  + (size_t)(wm * 32 + lr) * lda + lq * 8;
    const f16* a1 = a0 + (size_t)16 * lda;
    const f16* b0 = Bt + (size_t)(wn * 64 + lr) * ldb + lq * 8;

    f32x4 acc[2][4] = {};
#pragma unroll 2
    for (int k0 = 0; k0 < K; k0 += 32) {
        f16x8 af0 = *(const f16x8*)(a0 + k0);
        f16x8 af1 = *(const f16x8*)(a1 + k0);
        f16x8 bf[4];
#pragma unroll
        for (int ni = 0; ni < 4; ++ni)
            bf[ni] = *(const f16x8*)(b0 + (size_t)ni * 16 * ldb + k0);
#pragma unroll
        for (int ni = 0; ni < 4; ++ni) {
            acc[0][ni] = __builtin_amdgcn_mfma_f32_16x16x32_f16(af0, bf[ni], acc[0][ni], 0, 0, 0);
            acc[1][ni] = __builtin_amdgcn_mfma_f32_16x16x32_f16(af1, bf[ni], acc[1][ni], 0, 0, 0);
        }
    }
#pragma unroll
    for (int mi = 0; mi < 2; ++mi)
#pragma unroll
        for (int ni = 0; ni < 4; ++ni)
#pragma unroll
            for (int r = 0; r < 4; ++r) {
                int row = wm * 32 + mi * 16 + lq * 4 + r;
                int col = wn * 64 + ni * 16 + lr;
                C[(size_t)row * ldc + col] = acc[mi][ni][r];
            }
}

// ---------------------------------------------------------------------------
// 4) s1[n] = h[n]·a[0:H], s2[n] = h[n]·a[H:2H]
// ---------------------------------------------------------------------------
__global__ __launch_bounds__(256) void dot_s(const float* __restrict__ h,
                                             const float* __restrict__ a,
                                             float* __restrict__ s1,
                                             float* __restrict__ s2) {
    int n = blockIdx.x, t = threadIdx.x;
    float p1 = 0.f, p2 = 0.f;
    for (int c = t; c < HDIM; c += 256) {
        float hv = h[(size_t)n * HDIM + c];
        p1 += hv * a[c];
        p2 += hv * a[HDIM + c];
    }
    __shared__ float r1[256], r2[256];
    r1[t] = p1; r2[t] = p2;
    __syncthreads();
    for (int s = 128; s > 0; s >>= 1) {
        if (t < s) { r1[t] += r1[t + s]; r2[t] += r2[t + s]; }
        __syncthreads();
    }
    if (t == 0) { s1[n] = r1[0]; s2[n] = r2[0]; }
}

// ---------------------------------------------------------------------------
// 5) init dense buffers (ws is poisoned 0xAA every call — must re-init)
// ---------------------------------------------------------------------------
__global__ __launch_bounds__(256) void init_dense(float* __restrict__ e,
                                                  float* __restrict__ adj,
                                                  int* __restrict__ winner,
                                                  unsigned* __restrict__ amax) {
    int idx = blockIdx.x * 256 + threadIdx.x;    // grid sized exactly NN
    e[idx] = 0.f; adj[idx] = 0.f; winner[idx] = -1;
    if (idx == 0) *amax = 0u;
}

// 6) last-write-wins resolution: winner[r,c] = max edge index k hitting (r,c)
__global__ __launch_bounds__(256) void scatter_winner(const int* __restrict__ er,
                                                      const int* __restrict__ ec,
                                                      int* __restrict__ winner) {
    int k = blockIdx.x * 256 + threadIdx.x;
    atomicMax(&winner[er[k] * N_NODES + ec[k]], k);
}

// 7) winners write e (leaky_relu(s1[r]+s2[c])) and adj (2*adj_vals), track max
__global__ __launch_bounds__(256) void scatter_vals(const int* __restrict__ er,
                                                    const int* __restrict__ ec,
                                                    const float* __restrict__ adj_vals,
                                                    const int* __restrict__ winner,
                                                    const float* __restrict__ s1,
                                                    const float* __restrict__ s2,
                                                    float* __restrict__ e,
                                                    float* __restrict__ adj,
                                                    unsigned* __restrict__ amax) {
    int k = blockIdx.x * 256 + threadIdx.x;
    int r = er[k], c = ec[k];
    int idx = r * N_NODES + c;
    if (winner[idx] == k) {
        float ev = s1[r] + s2[c];
        e[idx] = ev > 0.f ? ev : 0.2f * ev;
        float av = adj_vals[k] * 2.0f;
        adj[idx] = av;
        atomicMax(amax, __float_as_uint(av));   // av >= 0: uint order == float order
    }
}

// ---------------------------------------------------------------------------
// 8) row softmax over dense 512 row; emit att (f16 for GEMM2) and
//    new_adj = att * adj/amax  (amin==0 exactly: structural zeros exist)
// ---------------------------------------------------------------------------
__global__ __launch_bounds__(256) void softmax_row(const float* __restrict__ e,
                                                   const float* __restrict__ adj,
                                                   const unsigned* __restrict__ amax_u,
                                                   f16* __restrict__ att_h,
                                                   float* __restrict__ new_adj) {
    int i = blockIdx.x, t = threadIdx.x;
    size_t base = (size_t)i * N_NODES;
    float e0 = e[base + t], e1 = e[base + t + 256];
    __shared__ float red[256];
    red[t] = fmaxf(e0, e1);
    __syncthreads();
    for (int s = 128; s > 0; s >>= 1) { if (t < s) red[t] = fmaxf(red[t], red[t + s]); __syncthreads(); }
    float m = red[0];
    __syncthreads();
    float p0 = expf(e0 - m), p1 = expf(e1 - m);
    red[t] = p0 + p1;
    __syncthreads();
    for (int s = 128; s > 0; s >>= 1) { if (t < s) red[t] += red[t + s]; __syncthreads(); }
    float denom = red[0];
    float am = __uint_as_float(*amax_u);
    float a0 = p0 / denom, a1 = p1 / denom;
    att_h[base + t] = (f16)a0;
    att_h[base + t + 256] = (f16)a1;
    new_adj[base + t]       = a0 * (adj[base + t] / am);
    new_adj[base + t + 256] = a1 * (adj[base + t + 256] / am);
}

// 9) ht[c][r] = (f16) h[r][c]   (for GEMM2 B-operand)
__global__ __launch_bounds__(256) void transpose_h(const float* __restrict__ h,
                                                   f16* __restrict__ ht) {
    __shared__ float tile[64][65];
    int r0 = blockIdx.x * 64, c0 = blockIdx.y * 64;
    int tx = threadIdx.x & 63, ty = threadIdx.x >> 6;
#pragma unroll
    for (int r = 0; r < 16; ++r) {
        int row = ty + (r << 2);
        tile[row][tx] = h[(size_t)(r0 + row) * HDIM + c0 + tx];
    }
    __syncthreads();
#pragma unroll
    for (int r = 0; r < 16; ++r) {
        int row = ty + (r << 2);
        ht[(size_t)(c0 + row) * N_NODES + r0 + tx] = (f16)tile[tx][row];
    }
}

// ---------------------------------------------------------------------------
// 10) out = lin_w @ hp_flat : 513 rows x 524288. THE memory-bound stage
//     (1.076 GB). Blocks: (chunk, row); deterministic partial sums.
// ---------------------------------------------------------------------------
__global__ __launch_bounds__(256) void matvec_partial(const float* __restrict__ lin_w,
                                                      const float* __restrict__ v,
                                                      float* __restrict__ partial) {
    int row = blockIdx.y, chunk = blockIdx.x, t = threadIdx.x;
    const float* wrow = lin_w + (size_t)row * NH + (size_t)chunk * CHUNK_LEN;
    const float* vv = v + (size_t)chunk * CHUNK_LEN;
    float acc = 0.f;
#pragma unroll
    for (int it = 0; it < 4; ++it) {
        int c = it * 1024 + t * 4;
        float4 w4 = *(const float4*)(wrow + c);
        float4 v4 = *(const float4*)(vv + c);
        acc += w4.x * v4.x + w4.y * v4.y + w4.z * v4.z + w4.w * v4.w;
    }
    __shared__ float red[256];
    red[t] = acc;
    __syncthreads();
    for (int s = 128; s > 0; s >>= 1) { if (t < s) red[t] += red[t + s]; __syncthreads(); }
    if (t == 0) partial[row * CHUNKS + chunk] = red[0];
}

// 11) per-row reduce of partials + bias
__global__ __launch_bounds__(128) void reduce_rows(const float* __restrict__ partial,
                                                   const float* __restrict__ lin_b,
                                                   float* __restrict__ out_raw) {
    int row = blockIdx.x, t = threadIdx.x;   // 128 threads
    __shared__ float red[128];
    red[t] = partial[row * CHUNKS + t];
    __syncthreads();
    for (int s = 64; s > 0; s >>= 1) { if (t < s) red[t] += red[t + s]; __syncthreads(); }
    if (t == 0) out_raw[row] = red[0] + lin_b[row];
}

// 12) min-max normalize 513 values (single block)
__global__ __launch_bounds__(1024) void finalize(const float* __restrict__ out_raw,
                                                 float* __restrict__ out_norm) {
    int t = threadIdx.x;   // 1024
    float v = (t < NP1) ? out_raw[t] : 0.f;
    __shared__ float rmin[1024], rmax[1024];
    rmin[t] = (t < NP1) ? v :  3.4e38f;
    rmax[t] = (t < NP1) ? v : -3.4e38f;
    __syncthreads();
    for (int s = 512; s > 0; s >>= 1) {
        if (t < s) {
            rmin[t] = fminf(rmin[t], rmin[t + s]);
            rmax[t] = fmaxf(rmax[t], rmax[t + s]);
        }
        __syncthreads();
    }
    float mn = rmin[0], mx = rmax[0];
    float denom = mx - mn;
    if (t < NP1) out_norm[t] = (denom == 0.f) ? 0.5f : (v - mn) / denom;
}

// ---------------------------------------------------------------------------
extern "C" void kernel_launch(void* const* d_in, const int* in_sizes, int n_in,
                              void* d_out, int out_size, void* d_ws, size_t ws_size,
                              hipStream_t stream) {
    const float* img      = (const float*)d_in[0];
    const int*   er       = (const int*)  d_in[1];
    const int*   ec       = (const int*)  d_in[2];
    const float* adj_vals = (const float*)d_in[3];
    const float* X        = (const float*)d_in[4];
    const float* W        = (const float*)d_in[5];
    const float* a        = (const float*)d_in[6];
    const float* lin_w    = (const float*)d_in[7];
    const float* lin_b    = (const float*)d_in[8];
    float* out = (float*)d_out;              // [NN new_adj | NP1 normalized]

    char* ws = (char*)d_ws;
    size_t off = 0;
    auto alloc = [&](size_t bytes) {
        void* p = ws + off;
        off = (off + bytes + 255) & ~(size_t)255;
        return p;
    };
    f16*      A_h    = (f16*)     alloc((size_t)N_NODES * K1 * 2);      // 4 MB
    f16*      Wt_h   = (f16*)     alloc((size_t)HDIM * K1 * 2);         // 8 MB
    float*    h      = (float*)   alloc((size_t)N_NODES * HDIM * 4);    // 2 MB
    f16*      ht     = (f16*)     alloc((size_t)HDIM * N_NODES * 2);    // 1 MB
    f16*      att_h  = (f16*)     alloc((size_t)NN * 2);                // 0.5 MB
    float*    hp     = (float*)   alloc((size_t)NN * 4 * 2);            // 2 MB (512x1024)
    float*    e      = (float*)   alloc((size_t)NN * 4);                // 1 MB
    float*    adj    = (float*)   alloc((size_t)NN * 4);                // 1 MB
    int*      winner = (int*)     alloc((size_t)NN * 4);                // 1 MB
    float*    s1     = (float*)   alloc(N_NODES * 4);
    float*    s2     = (float*)   alloc(N_NODES * 4);
    unsigned* amax   = (unsigned*)alloc(256);
    float*    part   = (float*)   alloc((size_t)NP1 * CHUNKS * 4);
    float*    outraw = (float*)   alloc(NP1 * 4);

    build_A  <<<(N_NODES * K1) / 256, 256, 0, stream>>>(X, img, A_h);
    build_Wt <<<dim3(K1 / 64, HDIM / 64), 256, 0, stream>>>(W, Wt_h);
    // h = A @ W : M=512 N=1024 K=4096 ; waves = 16*16 = 256 -> 64 blocks
    gemm_f16 <<<64, 256, 0, stream>>>(A_h, Wt_h, h, HDIM, K1, K1, K1, HDIM);
    dot_s    <<<N_NODES, 256, 0, stream>>>(h, a, s1, s2);
    init_dense<<<NN / 256, 256, 0, stream>>>(e, adj, winner, amax);
    scatter_winner<<<EDGES / 256, 256, 0, stream>>>(er, ec, winner);
    scatter_vals  <<<EDGES / 256, 256, 0, stream>>>(er, ec, adj_vals, winner, s1, s2, e, adj, amax);
    softmax_row   <<<N_NODES, 256, 0, stream>>>(e, adj, amax, att_h, out);
    transpose_h   <<<dim3(N_NODES / 64, HDIM / 64), 256, 0, stream>>>(h, ht);
    // hp = att @ h : M=512 N=1024 K=512 -> 64 blocks
    gemm_f16 <<<64, 256, 0, stream>>>(att_h, ht, hp, HDIM, N_NODES, N_NODES, N_NODES, HDIM);
    matvec_partial<<<dim3(CHUNKS, NP1), 256, 0, stream>>>(lin_w, hp, part);
    reduce_rows   <<<NP1, 128, 0, stream>>>(part, lin_b, outraw);
    finalize      <<<1, 1024, 0, stream>>>(outraw, out + NN);
}